// Round 1
// 205.430 us; speedup vs baseline: 1.0540x; 1.0540x over previous
//
#include <hip/hip_runtime.h>
#include <hip/hip_bf16.h>

// ---------------------------------------------------------------------------
// GCN: h = relu(gcnconv(x,W1,b1)); z = gcnconv(h,W2,b2); out[e]=dot(z[s],z[d])
// CSR build = bucketed counting sort, 4 kernels: hist(+bucket sums) ->
// rowscan -> reorder -> bucket_csr. part entries packed (row<<8 | col&255).
// gemm1 = bf16 MFMA (16x16x32): A direct from fp32 x (cvt in regs), B from
// pre-packed fragment-layout bf16 W1 (32KB, cache-resident), no LDS/barriers.
// R10: gemm2 FUSED into agg1 via MFMA. agg1 restructured: wave owns 16 nodes,
// 4 lanes/node, lane (m+16q) owns feat slices q*8..+7 / 32+q*8..+7 -- exactly
// the 16x16x32 bf16 A-fragment layout. After agg+bias+relu, 8 MFMAs against
// packed W2 give layer-2 rows in-register (kills gemm_tile + h buffer + 32MB
// traffic). pack kernel also zeroes bsums (drops the memset dispatch): 9
// dispatches total.
// Lessons kept: R9 edge-parallel LDS-atomic agg 7x worse; R5 no __shfl
// across group-divergent tails; R3 block-owned windows for random writes.
// ---------------------------------------------------------------------------

constexpr int NC = 512;      // edge chunks (= hist/reorder grid)
constexpr int NBPAD = 256;   // padded bucket count (>= 196 actual)
constexpr int BSHIFT = 8;    // 256 nodes per bucket

using short8 = __attribute__((ext_vector_type(8))) short;
using f32x4 = __attribute__((ext_vector_type(4))) float;

__device__ __forceinline__ unsigned short f2bf(float f) {   // RNE
    unsigned u = __float_as_uint(f);
    return (unsigned short)((u + 0x7FFF + ((u >> 16) & 1)) >> 16);
}
__device__ __forceinline__ float bf2f(unsigned short h) {
    return __uint_as_float(((unsigned)h) << 16);
}
__device__ __forceinline__ float4 bf4_to_f4(ushort4 u) {
    return make_float4(bf2f(u.x), bf2f(u.y), bf2f(u.z), bf2f(u.w));
}

// histCM[c*NBPAD+b] = bucket-b count in chunk c; bsums[b] = bucket totals.
__global__ __launch_bounds__(256) void hist_kernel(const int* __restrict__ col,
                                                   int* __restrict__ histCM,
                                                   int* __restrict__ bsums, int E, int CE) {
    __shared__ int hl[NBPAD];
    const int t = threadIdx.x, c = blockIdx.x;
    hl[t] = 0;
    __syncthreads();
    const int s = c * CE, e = min(E, s + CE);
    for (int i = s + t; i < e; i += 256) atomicAdd(&hl[col[i] >> BSHIFT], 1);
    __syncthreads();
    const int v = hl[t];
    histCM[c * NBPAD + t] = v;
    if (v) atomicAdd(&bsums[t], v);
}

// Block b: bucket base = sum(bsums[k<b]) (masked reduce), then exclusive scan
// of the bucket's NC chunk counts (2/thread) -> offsBM[b*NC+c].
__global__ __launch_bounds__(256) void rowscan_kernel(const int* __restrict__ histCM,
                                                      const int* __restrict__ bsums,
                                                      int* __restrict__ offsBM) {
    __shared__ int red[256];
    __shared__ int sc[256];
    const int t = threadIdx.x, b = blockIdx.x;
    red[t] = (t < b) ? bsums[t] : 0;
    __syncthreads();
    for (int off = 128; off > 0; off >>= 1) {
        if (t < off) red[t] += red[t + off];
        __syncthreads();
    }
    const int base = red[0];
    const int a0 = histCM[(2 * t) * NBPAD + b];
    const int a1 = histCM[(2 * t + 1) * NBPAD + b];
    const int ps = a0 + a1;
    sc[t] = ps;
    __syncthreads();
    for (int off = 1; off < 256; off <<= 1) {
        int u = (t >= off) ? sc[t - off] : 0;
        __syncthreads();
        sc[t] += u;
        __syncthreads();
    }
    const int excl = sc[t] - ps;
    offsBM[b * NC + 2 * t] = base + excl;
    offsBM[b * NC + 2 * t + 1] = base + excl + a0;
}

// Scatter packed (row<<8 | col&255) into per-(bucket,chunk) runs of part[].
__global__ __launch_bounds__(256) void reorder_kernel(const int* __restrict__ row,
                                                      const int* __restrict__ col,
                                                      const int* __restrict__ offsBM,
                                                      int* __restrict__ part, int E, int CE) {
    __shared__ int cur[NBPAD];
    const int t = threadIdx.x, c = blockIdx.x;
    cur[t] = offsBM[t * NC + c];
    __syncthreads();
    const int s = c * CE, e = min(E, s + CE);
    for (int i = s + t; i < e; i += 256) {
        const int r = row[i], cl = col[i];
        const int p = atomicAdd(&cur[cl >> BSHIFT], 1);
        part[p] = (r << 8) | (cl & 255);   // row < 65536 fits 16 bits
    }
}

// One block per bucket: LDS degree count -> LDS scan -> offs/dis -> scatter
// rows into the bucket's private csr window.
__global__ __launch_bounds__(256) void bucket_csr_kernel(const int* __restrict__ part,
                                                         const int* __restrict__ offsBM,
                                                         int* __restrict__ csr,
                                                         int* __restrict__ offs,
                                                         float* __restrict__ dis,
                                                         int N, int E, int nbk) {
    __shared__ int cnt[256];
    __shared__ int sc[256];
    const int t = threadIdx.x, b = blockIdx.x;
    const int base = b << BSHIFT;
    const int bstart = offsBM[b * NC];
    const int bend = (b + 1 < NBPAD) ? offsBM[(b + 1) * NC] : E;
    const int m = bend - bstart;
    cnt[t] = 0;
    __syncthreads();
    for (int i = t; i < m; i += 256) atomicAdd(&cnt[part[bstart + i] & 255], 1);
    __syncthreads();
    const int v = cnt[t];
    sc[t] = v;
    __syncthreads();
    for (int off = 1; off < 256; off <<= 1) {
        int u = (t >= off) ? sc[t - off] : 0;
        __syncthreads();
        sc[t] += u;
        __syncthreads();
    }
    const int excl = sc[t] - v;
    const int node = base + t;
    if (node < N) {
        offs[node] = bstart + excl;
        dis[node] = rsqrtf((float)(v + 1));   // +1 = self loop
    }
    sc[t] = excl;          // repurpose as scatter cursor
    __syncthreads();
    for (int i = t; i < m; i += 256) {
        const int pc = part[bstart + i];
        const int p = atomicAdd(&sc[pc & 255], 1);
        csr[bstart + p] = pc >> 8;
    }
    if (b == nbk - 1 && t == 0) offs[N] = E;
}

// Pack W1[256][64] and W2[64][64] fp32 -> bf16 in B-fragment layout:
// Wp[((k>>3)*64 + c)*8 + (k&7)] so a lane's 8 k-consecutive elements for a
// fixed column are one 16B load. Block 0 also zeroes bsums (kills the
// memset dispatch). Grid = 2 blocks.
__global__ __launch_bounds__(256) void pack_kernel(const float* __restrict__ W1,
                                                   const float* __restrict__ W2,
                                                   unsigned short* __restrict__ Wp1,
                                                   unsigned short* __restrict__ Wp2,
                                                   int* __restrict__ bsums) {
    const int k = threadIdx.x;
    if (blockIdx.x == 0) {
        bsums[k] = 0;
        for (int c = 0; c < 64; ++c)
            Wp1[((k >> 3) * 64 + c) * 8 + (k & 7)] = f2bf(W1[k * 64 + c]);
    } else if (k < 64) {
        for (int c = 0; c < 64; ++c)
            Wp2[((k >> 3) * 64 + c) * 8 + (k & 7)] = f2bf(W2[k * 64 + c]);
    }
}

// gemm1 via bf16 MFMA 16x16x32. Block = 4 waves; wave = 16 rows x 64 cols
// (4 ctiles of 16). A: lane m=lane&15, quad=lane>>4, k=ks*32+quad*8+j, loaded
// from fp32 x and cvt'd. B: Wp fragment-layout 16B loads (n=lane&15).
// C/D: col=lane&15, row=quad*4+reg (m89-verified). Epilogue: dis-scale+bf16.
template <int K>
__global__ __launch_bounds__(256) void gemm_mfma(const float* __restrict__ X,
                                                 const unsigned short* __restrict__ Wp,
                                                 const float* __restrict__ rowscale,
                                                 unsigned short* __restrict__ Y, int nrows) {
    const int tid = threadIdx.x;
    const int wv = tid >> 6;
    const int lane = tid & 63;
    const int m = lane & 15;
    const int quad = lane >> 4;
    const int rowbase = blockIdx.x * 64 + wv * 16;

    int grow = rowbase + m;
    if (grow >= nrows) grow = nrows - 1;   // clamp; stores guarded
    const float* xrow = X + (long)grow * K + quad * 8;

    f32x4 acc0 = {0.f, 0.f, 0.f, 0.f};
    f32x4 acc1 = acc0, acc2 = acc0, acc3 = acc0;

    #pragma unroll
    for (int ks = 0; ks < K / 32; ++ks) {
        const float4 a0 = *(const float4*)(xrow + ks * 32);
        const float4 a1 = *(const float4*)(xrow + ks * 32 + 4);
        short8 af;
        af[0] = (short)f2bf(a0.x); af[1] = (short)f2bf(a0.y);
        af[2] = (short)f2bf(a0.z); af[3] = (short)f2bf(a0.w);
        af[4] = (short)f2bf(a1.x); af[5] = (short)f2bf(a1.y);
        af[6] = (short)f2bf(a1.z); af[7] = (short)f2bf(a1.w);
        const unsigned short* bp = Wp + (size_t)((ks * 4 + quad) * 64) * 8;
        const short8 b0 = *(const short8*)(bp + (0 * 16 + m) * 8);
        const short8 b1 = *(const short8*)(bp + (1 * 16 + m) * 8);
        const short8 b2 = *(const short8*)(bp + (2 * 16 + m) * 8);
        const short8 b3 = *(const short8*)(bp + (3 * 16 + m) * 8);
        acc0 = __builtin_amdgcn_mfma_f32_16x16x32_bf16(af, b0, acc0, 0, 0, 0);
        acc1 = __builtin_amdgcn_mfma_f32_16x16x32_bf16(af, b1, acc1, 0, 0, 0);
        acc2 = __builtin_amdgcn_mfma_f32_16x16x32_bf16(af, b2, acc2, 0, 0, 0);
        acc3 = __builtin_amdgcn_mfma_f32_16x16x32_bf16(af, b3, acc3, 0, 0, 0);
    }

    #pragma unroll
    for (int reg = 0; reg < 4; ++reg) {
        const int orow = rowbase + quad * 4 + reg;
        if (orow < nrows) {
            const float d = rowscale[orow];
            unsigned short* yp = Y + (size_t)orow * 64 + m;
            yp[0]  = f2bf(d * acc0[reg]);
            yp[16] = f2bf(d * acc1[reg]);
            yp[32] = f2bf(d * acc2[reg]);
            yp[48] = f2bf(d * acc3[reg]);
        }
    }
}

__device__ __forceinline__ void acc8(float* a, short8 v) {
    #pragma unroll
    for (int j = 0; j < 8; ++j) a[j] += bf2f((unsigned short)v[j]);
}

// Fused agg1 + gemm2. Wave owns 16 nodes; lane (m + 16q) owns node m's
// feature slices [q*8, q*8+8) and [32+q*8, 32+q*8+8) -- exactly the
// 16x16x32 bf16 A-fragment layout (lane m, quad q holds k=ks*32+q*8+j).
// Aggregation: per edge, 4 lanes read 2x16B = full 128B row (4x fewer load
// instructions than the 16-lane-group layout). 4-deep unroll + index
// prefetch (per-lane loop-carried chain). Epilogue: h = relu(di*acc + b1)
// -> bf16 A-frags -> 8 MFMAs vs packed W2 -> dis-scale -> bf16 xs2.
__global__ __launch_bounds__(256) void agg_gemm_fused(const unsigned short* __restrict__ xs,
                                                      const int* __restrict__ csr,
                                                      const int* __restrict__ offs,
                                                      const float* __restrict__ dis,
                                                      const float* __restrict__ b1,
                                                      const unsigned short* __restrict__ Wp2,
                                                      unsigned short* __restrict__ Y, int n) {
    const int tid = threadIdx.x;
    const int wv = tid >> 6;
    const int lane = tid & 63;
    const int m = lane & 15;
    const int q = lane >> 4;
    const int rowbase = blockIdx.x * 64 + wv * 16;

    int i = rowbase + m;
    if (i >= n) i = n - 1;           // clamp (dup work; stores guarded)
    const int off_lo = q * 8;        // feats off_lo..+7 (lo), 32+off_lo..+7 (hi)

    // self loop init
    float alo[8], ahi[8];
    {
        const unsigned short* xrow = xs + (size_t)i * 64;
        const short8 s0 = *(const short8*)(xrow + off_lo);
        const short8 s1 = *(const short8*)(xrow + 32 + off_lo);
        #pragma unroll
        for (int j = 0; j < 8; ++j) { alo[j] = bf2f((unsigned short)s0[j]); ahi[j] = bf2f((unsigned short)s1[j]); }
    }

    const int s = offs[i];
    const int e = offs[i + 1];
    int j = s;
    int r0 = 0, r1 = 0, r2 = 0, r3 = 0;
    if (j + 3 < e) { r0 = csr[j]; r1 = csr[j + 1]; r2 = csr[j + 2]; r3 = csr[j + 3]; }
    while (j + 3 < e) {
        const int jn = j + 4;
        const int c0 = min(jn,     e - 1), c1 = min(jn + 1, e - 1);
        const int c2 = min(jn + 2, e - 1), c3 = min(jn + 3, e - 1);
        const int n0 = csr[c0], n1 = csr[c1], n2 = csr[c2], n3 = csr[c3];
        const short8 v0l = *(const short8*)(xs + (size_t)r0 * 64 + off_lo);
        const short8 v0h = *(const short8*)(xs + (size_t)r0 * 64 + 32 + off_lo);
        const short8 v1l = *(const short8*)(xs + (size_t)r1 * 64 + off_lo);
        const short8 v1h = *(const short8*)(xs + (size_t)r1 * 64 + 32 + off_lo);
        const short8 v2l = *(const short8*)(xs + (size_t)r2 * 64 + off_lo);
        const short8 v2h = *(const short8*)(xs + (size_t)r2 * 64 + 32 + off_lo);
        const short8 v3l = *(const short8*)(xs + (size_t)r3 * 64 + off_lo);
        const short8 v3h = *(const short8*)(xs + (size_t)r3 * 64 + 32 + off_lo);
        acc8(alo, v0l); acc8(ahi, v0h);
        acc8(alo, v1l); acc8(ahi, v1h);
        acc8(alo, v2l); acc8(ahi, v2h);
        acc8(alo, v3l); acc8(ahi, v3h);
        r0 = n0; r1 = n1; r2 = n2; r3 = n3;
        j = jn;
    }
    for (; j < e; ++j) {
        const int r = csr[j];
        const short8 vl = *(const short8*)(xs + (size_t)r * 64 + off_lo);
        const short8 vh = *(const short8*)(xs + (size_t)r * 64 + 32 + off_lo);
        acc8(alo, vl); acc8(ahi, vh);
    }

    // h = relu(di * acc + b1)  -> bf16 A-fragments (ks=0: ha, ks=1: hb)
    const float di = dis[i];
    float bl[8], bh[8];
    *(float4*)&bl[0] = *(const float4*)(b1 + off_lo);
    *(float4*)&bl[4] = *(const float4*)(b1 + off_lo + 4);
    *(float4*)&bh[0] = *(const float4*)(b1 + 32 + off_lo);
    *(float4*)&bh[4] = *(const float4*)(b1 + 32 + off_lo + 4);
    short8 ha, hb;
    #pragma unroll
    for (int jj = 0; jj < 8; ++jj) {
        ha[jj] = (short)f2bf(fmaxf(fmaf(alo[jj], di, bl[jj]), 0.f));
        hb[jj] = (short)f2bf(fmaxf(fmaf(ahi[jj], di, bh[jj]), 0.f));
    }

    // y = h @ W2 via 8 MFMAs (4 col tiles x 2 k-steps)
    const unsigned short* bplo = Wp2 + (size_t)(q * 64) * 8;        // ks=0
    const unsigned short* bphi = Wp2 + (size_t)((4 + q) * 64) * 8;  // ks=1
    f32x4 c0 = {0.f, 0.f, 0.f, 0.f};
    f32x4 c1 = c0, c2 = c0, c3 = c0;
    const short8 w0l = *(const short8*)(bplo + (0 * 16 + m) * 8);
    const short8 w1l = *(const short8*)(bplo + (1 * 16 + m) * 8);
    const short8 w2l = *(const short8*)(bplo + (2 * 16 + m) * 8);
    const short8 w3l = *(const short8*)(bplo + (3 * 16 + m) * 8);
    const short8 w0h = *(const short8*)(bphi + (0 * 16 + m) * 8);
    const short8 w1h = *(const short8*)(bphi + (1 * 16 + m) * 8);
    const short8 w2h = *(const short8*)(bphi + (2 * 16 + m) * 8);
    const short8 w3h = *(const short8*)(bphi + (3 * 16 + m) * 8);
    c0 = __builtin_amdgcn_mfma_f32_16x16x32_bf16(ha, w0l, c0, 0, 0, 0);
    c0 = __builtin_amdgcn_mfma_f32_16x16x32_bf16(hb, w0h, c0, 0, 0, 0);
    c1 = __builtin_amdgcn_mfma_f32_16x16x32_bf16(ha, w1l, c1, 0, 0, 0);
    c1 = __builtin_amdgcn_mfma_f32_16x16x32_bf16(hb, w1h, c1, 0, 0, 0);
    c2 = __builtin_amdgcn_mfma_f32_16x16x32_bf16(ha, w2l, c2, 0, 0, 0);
    c2 = __builtin_amdgcn_mfma_f32_16x16x32_bf16(hb, w2h, c2, 0, 0, 0);
    c3 = __builtin_amdgcn_mfma_f32_16x16x32_bf16(ha, w3l, c3, 0, 0, 0);
    c3 = __builtin_amdgcn_mfma_f32_16x16x32_bf16(hb, w3h, c3, 0, 0, 0);

    // epilogue: xs2[orow, c] = dis[orow] * y   (C layout: col=m, row=q*4+reg)
    #pragma unroll
    for (int reg = 0; reg < 4; ++reg) {
        const int orow = rowbase + q * 4 + reg;
        if (orow < n) {
            const float d2 = dis[orow];
            unsigned short* yp = Y + (size_t)orow * 64 + m;
            yp[0]  = f2bf(d2 * c0[reg]);
            yp[16] = f2bf(d2 * c1[reg]);
            yp[32] = f2bf(d2 * c2[reg]);
            yp[48] = f2bf(d2 * c3[reg]);
        }
    }
}

// One 16-lane group per node; lane fl owns feats fl*4..+3 (8B bf16).
// Features lane-parallel -> no reduction, no LDS. Index PREFETCH: next
// iteration's 4 csr indices load in parallel with current gathers, removing
// the 2-hop (index -> gather) serial latency from the loop-carried chain.
template <bool RELU, bool OUT_BF16>
__global__ __launch_bounds__(256) void agg_kernel(const unsigned short* __restrict__ xs,
                                                  const int* __restrict__ csr,
                                                  const int* __restrict__ offs,
                                                  const float* __restrict__ dis,
                                                  const float* __restrict__ bias,
                                                  void* __restrict__ out, int n) {
    const int t = threadIdx.x;
    const int fl = t & 15;
    const int i = blockIdx.x * 16 + (t >> 4);   // node per 16-lane group
    if (i >= n) return;                          // no barriers below: safe
    float4 acc = bf4_to_f4(*(const ushort4*)&xs[(long)i * 64 + fl * 4]);  // self loop
    const int s = offs[i];
    const int e = offs[i + 1];
    int j = s;
    int r0 = 0, r1 = 0, r2 = 0, r3 = 0;
    if (j + 3 < e) { r0 = csr[j]; r1 = csr[j + 1]; r2 = csr[j + 2]; r3 = csr[j + 3]; }
    while (j + 3 < e) {
        const int jn = j + 4;
        // prefetch next indices (clamped: always in-bounds, unused in tail)
        const int c0 = min(jn,     e - 1), c1 = min(jn + 1, e - 1);
        const int c2 = min(jn + 2, e - 1), c3 = min(jn + 3, e - 1);
        const int n0 = csr[c0], n1 = csr[c1], n2 = csr[c2], n3 = csr[c3];
        const float4 v0 = bf4_to_f4(*(const ushort4*)&xs[(long)r0 * 64 + fl * 4]);
        const float4 v1 = bf4_to_f4(*(const ushort4*)&xs[(long)r1 * 64 + fl * 4]);
        const float4 v2 = bf4_to_f4(*(const ushort4*)&xs[(long)r2 * 64 + fl * 4]);
        const float4 v3 = bf4_to_f4(*(const ushort4*)&xs[(long)r3 * 64 + fl * 4]);
        acc.x += (v0.x + v1.x) + (v2.x + v3.x);
        acc.y += (v0.y + v1.y) + (v2.y + v3.y);
        acc.z += (v0.z + v1.z) + (v2.z + v3.z);
        acc.w += (v0.w + v1.w) + (v2.w + v3.w);
        r0 = n0; r1 = n1; r2 = n2; r3 = n3;
        j = jn;
    }
    for (; j < e; ++j) {
        const int r = csr[j];
        const float4 v = bf4_to_f4(*(const ushort4*)&xs[(long)r * 64 + fl * 4]);
        acc.x += v.x; acc.y += v.y; acc.z += v.z; acc.w += v.w;
    }
    const float di = dis[i];
    const float4 b = *(const float4*)&bias[fl * 4];
    float4 o;
    o.x = fmaf(acc.x, di, b.x); o.y = fmaf(acc.y, di, b.y);
    o.z = fmaf(acc.z, di, b.z); o.w = fmaf(acc.w, di, b.w);
    if (RELU) {
        o.x = fmaxf(o.x, 0.f); o.y = fmaxf(o.y, 0.f);
        o.z = fmaxf(o.z, 0.f); o.w = fmaxf(o.w, 0.f);
    }
    if (OUT_BF16) {
        ushort4 ov;
        ov.x = f2bf(o.x); ov.y = f2bf(o.y); ov.z = f2bf(o.z); ov.w = f2bf(o.w);
        *(ushort4*)&((unsigned short*)out)[(long)i * 64 + fl * 4] = ov;
    } else {
        *(float4*)&((float*)out)[(long)i * 64 + fl * 4] = o;
    }
}

// 16 lanes per label edge: bf16 gathers of z[src], z[dst]; 4-step xor reduce
// (within-group shfl: all 16 source lanes share the group's control flow).
__global__ __launch_bounds__(256) void decode_kernel(const unsigned short* __restrict__ z,
                                                     const int* __restrict__ src,
                                                     const int* __restrict__ dst,
                                                     float* __restrict__ out, int L) {
    const int t = blockIdx.x * 256 + threadIdx.x;
    const int e = t >> 4;
    const int fl = t & 15;
    if (e >= L) return;
    const int s = src[e];
    const int d = dst[e];
    const float4 a = bf4_to_f4(*(const ushort4*)&z[(long)s * 64 + fl * 4]);
    const float4 b = bf4_to_f4(*(const ushort4*)&z[(long)d * 64 + fl * 4]);
    float p = a.x * b.x + a.y * b.y + a.z * b.z + a.w * b.w;
    p += __shfl_xor(p, 8); p += __shfl_xor(p, 4);
    p += __shfl_xor(p, 2); p += __shfl_xor(p, 1);
    if (fl == 0) out[e] = p;
}

extern "C" void kernel_launch(void* const* d_in, const int* in_sizes, int n_in,
                              void* d_out, int out_size, void* d_ws, size_t ws_size,
                              hipStream_t stream) {
    const float* x   = (const float*)d_in[0];
    const int*   ei  = (const int*)d_in[1];
    const int*   eli = (const int*)d_in[2];
    const float* W1  = (const float*)d_in[3];
    const float* b1  = (const float*)d_in[4];
    const float* W2  = (const float*)d_in[5];
    const float* b2  = (const float*)d_in[6];
    float* out = (float*)d_out;

    const int N = in_sizes[0] / 256;   // 50000 nodes (IN_CH = 256)
    const int E = in_sizes[1] / 2;     // 800000 edges
    const int L = in_sizes[2] / 2;     // 200000 label edges
    const int* row = ei;
    const int* col = ei + E;
    const int* src = eli;
    const int* dst = eli + L;

    char* w = (char*)d_ws;
    unsigned short* xs1 = (unsigned short*)w;  w += (size_t)N * 64 * 2;  // bf16 layer-1 pre-agg
    unsigned short* xs2 = (unsigned short*)w;  w += (size_t)N * 64 * 2;  // bf16 layer-2 pre-agg
    unsigned short* z = (unsigned short*)w;  w += (size_t)N * 64 * 2;    // bf16 layer-2 output
    int*   csr = (int*)w;    w += (size_t)E * 4;          // sources sorted by target
    int*   offs = (int*)w;   w += (size_t)(N + 1) * 4;    // CSR offsets (N+1)
    float* dis = (float*)w;  w += (size_t)N * 4;          // rsqrt(deg+1)
    int*   part = (int*)w;   w += (size_t)E * 4;          // packed (row<<8|col&255)
    int* histCM = (int*)w;   w += (size_t)NC * NBPAD * 4; // per-(chunk,bucket) counts
    int* offsBM = (int*)w;   w += (size_t)NBPAD * NC * 4; // per-(bucket,chunk) offsets
    int* bsums  = (int*)w;   w += NBPAD * 4;              // bucket totals
    unsigned short* Wp1 = (unsigned short*)w;  w += (size_t)256 * 64 * 2;  // packed bf16 W1
    unsigned short* Wp2 = (unsigned short*)w;  w += (size_t)64 * 64 * 2;   // packed bf16 W2

    const int CE = (E + NC - 1) / NC;
    const int nbk = (N + (1 << BSHIFT) - 1) >> BSHIFT;    // 196 buckets

    pack_kernel<<<2, 256, 0, stream>>>(W1, W2, Wp1, Wp2, bsums);
    hist_kernel<<<NC, 256, 0, stream>>>(col, histCM, bsums, E, CE);
    rowscan_kernel<<<NBPAD, 256, 0, stream>>>(histCM, bsums, offsBM);
    reorder_kernel<<<NC, 256, 0, stream>>>(row, col, offsBM, part, E, CE);
    bucket_csr_kernel<<<nbk, 256, 0, stream>>>(part, offsBM, csr, offs, dis, N, E, nbk);

    gemm_mfma<256><<<(N + 63) / 64, 256, 0, stream>>>(x, Wp1, dis, xs1, N);
    agg_gemm_fused<<<(N + 63) / 64, 256, 0, stream>>>(xs1, csr, offs, dis, b1, Wp2, xs2, N);
    agg_kernel<false, true><<<(N + 15) / 16, 256, 0, stream>>>(xs2, csr, offs, dis, b2, z, N);
    decode_kernel<<<(L + 15) / 16, 256, 0, stream>>>(z, src, dst, out, L);
}

// Round 2
// 198.644 us; speedup vs baseline: 1.0901x; 1.0342x over previous
//
#include <hip/hip_runtime.h>
#include <hip/hip_bf16.h>

// ---------------------------------------------------------------------------
// GCN: h = relu(gcnconv(x,W1,b1)); z = gcnconv(h,W2,b2); out[e]=dot(z[s],z[d])
// CSR build = bucketed counting sort, 4 kernels: hist(+bucket sums) ->
// rowscan -> reorder -> bucket_csr. part entries packed (row<<8 | col&255).
// gemm1 = bf16 MFMA (16x16x32): A direct from fp32 x (cvt in regs), B from
// pre-packed fragment-layout bf16 W1 (32KB, cache-resident), no LDS/barriers.
// R10: gemm2 fused into agg1 via MFMA (wave owns 16 nodes, 4 lanes/node =
// exactly the 16x16x32 A-fragment layout).
// R11: agg2 ported to the same wave layout (half the gather instructions of
// the 16-lane/node form, 16B stores); bucket_csr 256->1024 threads (was
// 1 wave/SIMD latency-bound); hist writes bucket-major histBM so rowscan
// reads coalesce; decode 8 lanes/edge short8 loads; pack parallelized.
// Lessons kept: R9 edge-parallel LDS-atomic agg 7x worse; R5 no __shfl
// across group-divergent tails; R3 block-owned windows for random writes.
// ---------------------------------------------------------------------------

constexpr int NC = 512;      // edge chunks (= hist/reorder grid)
constexpr int NBPAD = 256;   // padded bucket count (>= 196 actual)
constexpr int BSHIFT = 8;    // 256 nodes per bucket

using short8 = __attribute__((ext_vector_type(8))) short;
using f32x4 = __attribute__((ext_vector_type(4))) float;

__device__ __forceinline__ unsigned short f2bf(float f) {   // RNE
    unsigned u = __float_as_uint(f);
    return (unsigned short)((u + 0x7FFF + ((u >> 16) & 1)) >> 16);
}
__device__ __forceinline__ float bf2f(unsigned short h) {
    return __uint_as_float(((unsigned)h) << 16);
}
__device__ __forceinline__ float4 bf4_to_f4(ushort4 u) {
    return make_float4(bf2f(u.x), bf2f(u.y), bf2f(u.z), bf2f(u.w));
}

// Parallel pack: block 0 zeroes bsums; blocks 1..64 pack W1 (1 elem/thread);
// blocks 65..80 pack W2. Fragment layout Wp[((k>>3)*64 + c)*8 + (k&7)].
__global__ __launch_bounds__(256) void pack_kernel(const float* __restrict__ W1,
                                                   const float* __restrict__ W2,
                                                   unsigned short* __restrict__ Wp1,
                                                   unsigned short* __restrict__ Wp2,
                                                   int* __restrict__ bsums) {
    const int t = threadIdx.x, b = blockIdx.x;
    if (b == 0) {
        bsums[t] = 0;
    } else if (b <= 64) {
        const int idx = (b - 1) * 256 + t;     // k*64 + c, k<256
        const int k = idx >> 6, c = idx & 63;
        Wp1[((k >> 3) * 64 + c) * 8 + (k & 7)] = f2bf(W1[idx]);
    } else {
        const int idx = (b - 65) * 256 + t;    // k*64 + c, k<64
        const int k = idx >> 6, c = idx & 63;
        Wp2[((k >> 3) * 64 + c) * 8 + (k & 7)] = f2bf(W2[idx]);
    }
}

// histBM[b*NC+c] = bucket-b count in chunk c (bucket-MAJOR: uncoalesced
// stores here, coalesced reads in rowscan); bsums[b] = bucket totals.
__global__ __launch_bounds__(256) void hist_kernel(const int* __restrict__ col,
                                                   int* __restrict__ histBM,
                                                   int* __restrict__ bsums, int E, int CE) {
    __shared__ int hl[NBPAD];
    const int t = threadIdx.x, c = blockIdx.x;
    hl[t] = 0;
    __syncthreads();
    const int s = c * CE, e = min(E, s + CE);
    for (int i = s + t; i < e; i += 256) atomicAdd(&hl[col[i] >> BSHIFT], 1);
    __syncthreads();
    const int v = hl[t];
    histBM[t * NC + c] = v;
    if (v) atomicAdd(&bsums[t], v);
}

// Block b: bucket base = sum(bsums[k<b]) (masked reduce), then exclusive scan
// of the bucket's NC chunk counts (2/thread, coalesced int2) -> offsBM[b*NC+c].
__global__ __launch_bounds__(256) void rowscan_kernel(const int* __restrict__ histBM,
                                                      const int* __restrict__ bsums,
                                                      int* __restrict__ offsBM) {
    __shared__ int red[256];
    __shared__ int sc[256];
    const int t = threadIdx.x, b = blockIdx.x;
    red[t] = (t < b) ? bsums[t] : 0;
    __syncthreads();
    for (int off = 128; off > 0; off >>= 1) {
        if (t < off) red[t] += red[t + off];
        __syncthreads();
    }
    const int base = red[0];
    const int2 a = *(const int2*)&histBM[b * NC + 2 * t];
    const int a0 = a.x, a1 = a.y;
    const int ps = a0 + a1;
    sc[t] = ps;
    __syncthreads();
    for (int off = 1; off < 256; off <<= 1) {
        int u = (t >= off) ? sc[t - off] : 0;
        __syncthreads();
        sc[t] += u;
        __syncthreads();
    }
    const int excl = sc[t] - ps;
    offsBM[b * NC + 2 * t] = base + excl;
    offsBM[b * NC + 2 * t + 1] = base + excl + a0;
}

// Scatter packed (row<<8 | col&255) into per-(bucket,chunk) runs of part[].
__global__ __launch_bounds__(256) void reorder_kernel(const int* __restrict__ row,
                                                      const int* __restrict__ col,
                                                      const int* __restrict__ offsBM,
                                                      int* __restrict__ part, int E, int CE) {
    __shared__ int cur[NBPAD];
    const int t = threadIdx.x, c = blockIdx.x;
    cur[t] = offsBM[t * NC + c];
    __syncthreads();
    const int s = c * CE, e = min(E, s + CE);
    for (int i = s + t; i < e; i += 256) {
        const int r = row[i], cl = col[i];
        const int p = atomicAdd(&cur[cl >> BSHIFT], 1);
        part[p] = (r << 8) | (cl & 255);   // row < 65536 fits 16 bits
    }
}

// One 1024-thread block per bucket (4 waves/SIMD vs old 1: this kernel is
// latency-bound on global load -> LDS atomic): LDS degree count -> LDS scan
// (first 256 threads, all-thread barriers) -> offs/dis -> scatter rows.
__global__ __launch_bounds__(1024) void bucket_csr_kernel(const int* __restrict__ part,
                                                          const int* __restrict__ offsBM,
                                                          int* __restrict__ csr,
                                                          int* __restrict__ offs,
                                                          float* __restrict__ dis,
                                                          int N, int E, int nbk) {
    __shared__ int cnt[256];
    __shared__ int sc[256];
    const int t = threadIdx.x, b = blockIdx.x;
    const int base = b << BSHIFT;
    const int bstart = offsBM[b * NC];
    const int bend = (b + 1 < NBPAD) ? offsBM[(b + 1) * NC] : E;
    const int m = bend - bstart;
    if (t < 256) cnt[t] = 0;
    __syncthreads();
    for (int i = t; i < m; i += 1024) atomicAdd(&cnt[part[bstart + i] & 255], 1);
    __syncthreads();
    int v = 0;
    if (t < 256) { v = cnt[t]; sc[t] = v; }
    __syncthreads();
    for (int off = 1; off < 256; off <<= 1) {
        int u = 0;
        if (t >= off && t < 256) u = sc[t - off];
        __syncthreads();
        if (t < 256) sc[t] += u;
        __syncthreads();
    }
    if (t < 256) {
        const int excl = sc[t] - v;
        const int node = base + t;
        if (node < N) {
            offs[node] = bstart + excl;
            dis[node] = rsqrtf((float)(v + 1));   // +1 = self loop
        }
        sc[t] = excl;      // repurpose as scatter cursor
    }
    __syncthreads();
    for (int i = t; i < m; i += 1024) {
        const int pc = part[bstart + i];
        const int p = atomicAdd(&sc[pc & 255], 1);
        csr[bstart + p] = pc >> 8;
    }
    if (b == nbk - 1 && t == 0) offs[N] = E;
}

// gemm1 via bf16 MFMA 16x16x32. Block = 4 waves; wave = 16 rows x 64 cols
// (4 ctiles of 16). A: lane m=lane&15, quad=lane>>4, k=ks*32+quad*8+j, loaded
// from fp32 x and cvt'd. B: Wp fragment-layout 16B loads (n=lane&15).
// C/D: col=lane&15, row=quad*4+reg (m89-verified). Epilogue: dis-scale+bf16.
template <int K>
__global__ __launch_bounds__(256) void gemm_mfma(const float* __restrict__ X,
                                                 const unsigned short* __restrict__ Wp,
                                                 const float* __restrict__ rowscale,
                                                 unsigned short* __restrict__ Y, int nrows) {
    const int tid = threadIdx.x;
    const int wv = tid >> 6;
    const int lane = tid & 63;
    const int m = lane & 15;
    const int quad = lane >> 4;
    const int rowbase = blockIdx.x * 64 + wv * 16;

    int grow = rowbase + m;
    if (grow >= nrows) grow = nrows - 1;   // clamp; stores guarded
    const float* xrow = X + (long)grow * K + quad * 8;

    f32x4 acc0 = {0.f, 0.f, 0.f, 0.f};
    f32x4 acc1 = acc0, acc2 = acc0, acc3 = acc0;

    #pragma unroll
    for (int ks = 0; ks < K / 32; ++ks) {
        const float4 a0 = *(const float4*)(xrow + ks * 32);
        const float4 a1 = *(const float4*)(xrow + ks * 32 + 4);
        short8 af;
        af[0] = (short)f2bf(a0.x); af[1] = (short)f2bf(a0.y);
        af[2] = (short)f2bf(a0.z); af[3] = (short)f2bf(a0.w);
        af[4] = (short)f2bf(a1.x); af[5] = (short)f2bf(a1.y);
        af[6] = (short)f2bf(a1.z); af[7] = (short)f2bf(a1.w);
        const unsigned short* bp = Wp + (size_t)((ks * 4 + quad) * 64) * 8;
        const short8 b0 = *(const short8*)(bp + (0 * 16 + m) * 8);
        const short8 b1 = *(const short8*)(bp + (1 * 16 + m) * 8);
        const short8 b2 = *(const short8*)(bp + (2 * 16 + m) * 8);
        const short8 b3 = *(const short8*)(bp + (3 * 16 + m) * 8);
        acc0 = __builtin_amdgcn_mfma_f32_16x16x32_bf16(af, b0, acc0, 0, 0, 0);
        acc1 = __builtin_amdgcn_mfma_f32_16x16x32_bf16(af, b1, acc1, 0, 0, 0);
        acc2 = __builtin_amdgcn_mfma_f32_16x16x32_bf16(af, b2, acc2, 0, 0, 0);
        acc3 = __builtin_amdgcn_mfma_f32_16x16x32_bf16(af, b3, acc3, 0, 0, 0);
    }

    #pragma unroll
    for (int reg = 0; reg < 4; ++reg) {
        const int orow = rowbase + quad * 4 + reg;
        if (orow < nrows) {
            const float d = rowscale[orow];
            unsigned short* yp = Y + (size_t)orow * 64 + m;
            yp[0]  = f2bf(d * acc0[reg]);
            yp[16] = f2bf(d * acc1[reg]);
            yp[32] = f2bf(d * acc2[reg]);
            yp[48] = f2bf(d * acc3[reg]);
        }
    }
}

__device__ __forceinline__ void acc8(float* a, short8 v) {
    #pragma unroll
    for (int j = 0; j < 8; ++j) a[j] += bf2f((unsigned short)v[j]);
}

// Fused agg1 + gemm2. Wave owns 16 nodes; lane (m + 16q) owns node m's
// feature slices [q*8, q*8+8) and [32+q*8, 32+q*8+8) -- exactly the
// 16x16x32 bf16 A-fragment layout. Per edge, 4 lanes read 2x16B = full 128B
// row. 4-deep unroll + index prefetch. Epilogue: h = relu(di*acc + b1)
// -> bf16 A-frags -> 8 MFMAs vs packed W2 -> dis-scale -> bf16 xs2.
__global__ __launch_bounds__(256) void agg_gemm_fused(const unsigned short* __restrict__ xs,
                                                      const int* __restrict__ csr,
                                                      const int* __restrict__ offs,
                                                      const float* __restrict__ dis,
                                                      const float* __restrict__ b1,
                                                      const unsigned short* __restrict__ Wp2,
                                                      unsigned short* __restrict__ Y, int n) {
    const int tid = threadIdx.x;
    const int wv = tid >> 6;
    const int lane = tid & 63;
    const int m = lane & 15;
    const int q = lane >> 4;
    const int rowbase = blockIdx.x * 64 + wv * 16;

    int i = rowbase + m;
    if (i >= n) i = n - 1;           // clamp (dup work; stores guarded)
    const int off_lo = q * 8;        // feats off_lo..+7 (lo), 32+off_lo..+7 (hi)

    // self loop init
    float alo[8], ahi[8];
    {
        const unsigned short* xrow = xs + (size_t)i * 64;
        const short8 s0 = *(const short8*)(xrow + off_lo);
        const short8 s1 = *(const short8*)(xrow + 32 + off_lo);
        #pragma unroll
        for (int j = 0; j < 8; ++j) { alo[j] = bf2f((unsigned short)s0[j]); ahi[j] = bf2f((unsigned short)s1[j]); }
    }

    const int s = offs[i];
    const int e = offs[i + 1];
    int j = s;
    int r0 = 0, r1 = 0, r2 = 0, r3 = 0;
    if (j + 3 < e) { r0 = csr[j]; r1 = csr[j + 1]; r2 = csr[j + 2]; r3 = csr[j + 3]; }
    while (j + 3 < e) {
        const int jn = j + 4;
        const int c0 = min(jn,     e - 1), c1 = min(jn + 1, e - 1);
        const int c2 = min(jn + 2, e - 1), c3 = min(jn + 3, e - 1);
        const int n0 = csr[c0], n1 = csr[c1], n2 = csr[c2], n3 = csr[c3];
        const short8 v0l = *(const short8*)(xs + (size_t)r0 * 64 + off_lo);
        const short8 v0h = *(const short8*)(xs + (size_t)r0 * 64 + 32 + off_lo);
        const short8 v1l = *(const short8*)(xs + (size_t)r1 * 64 + off_lo);
        const short8 v1h = *(const short8*)(xs + (size_t)r1 * 64 + 32 + off_lo);
        const short8 v2l = *(const short8*)(xs + (size_t)r2 * 64 + off_lo);
        const short8 v2h = *(const short8*)(xs + (size_t)r2 * 64 + 32 + off_lo);
        const short8 v3l = *(const short8*)(xs + (size_t)r3 * 64 + off_lo);
        const short8 v3h = *(const short8*)(xs + (size_t)r3 * 64 + 32 + off_lo);
        acc8(alo, v0l); acc8(ahi, v0h);
        acc8(alo, v1l); acc8(ahi, v1h);
        acc8(alo, v2l); acc8(ahi, v2h);
        acc8(alo, v3l); acc8(ahi, v3h);
        r0 = n0; r1 = n1; r2 = n2; r3 = n3;
        j = jn;
    }
    for (; j < e; ++j) {
        const int r = csr[j];
        const short8 vl = *(const short8*)(xs + (size_t)r * 64 + off_lo);
        const short8 vh = *(const short8*)(xs + (size_t)r * 64 + 32 + off_lo);
        acc8(alo, vl); acc8(ahi, vh);
    }

    // h = relu(di * acc + b1)  -> bf16 A-fragments (ks=0: ha, ks=1: hb)
    const float di = dis[i];
    float bl[8], bh[8];
    *(float4*)&bl[0] = *(const float4*)(b1 + off_lo);
    *(float4*)&bl[4] = *(const float4*)(b1 + off_lo + 4);
    *(float4*)&bh[0] = *(const float4*)(b1 + 32 + off_lo);
    *(float4*)&bh[4] = *(const float4*)(b1 + 32 + off_lo + 4);
    short8 ha, hb;
    #pragma unroll
    for (int jj = 0; jj < 8; ++jj) {
        ha[jj] = (short)f2bf(fmaxf(fmaf(alo[jj], di, bl[jj]), 0.f));
        hb[jj] = (short)f2bf(fmaxf(fmaf(ahi[jj], di, bh[jj]), 0.f));
    }

    // y = h @ W2 via 8 MFMAs (4 col tiles x 2 k-steps)
    const unsigned short* bplo = Wp2 + (size_t)(q * 64) * 8;        // ks=0
    const unsigned short* bphi = Wp2 + (size_t)((4 + q) * 64) * 8;  // ks=1
    f32x4 c0 = {0.f, 0.f, 0.f, 0.f};
    f32x4 c1 = c0, c2 = c0, c3 = c0;
    const short8 w0l = *(const short8*)(bplo + (0 * 16 + m) * 8);
    const short8 w1l = *(const short8*)(bplo + (1 * 16 + m) * 8);
    const short8 w2l = *(const short8*)(bplo + (2 * 16 + m) * 8);
    const short8 w3l = *(const short8*)(bplo + (3 * 16 + m) * 8);
    const short8 w0h = *(const short8*)(bphi + (0 * 16 + m) * 8);
    const short8 w1h = *(const short8*)(bphi + (1 * 16 + m) * 8);
    const short8 w2h = *(const short8*)(bphi + (2 * 16 + m) * 8);
    const short8 w3h = *(const short8*)(bphi + (3 * 16 + m) * 8);
    c0 = __builtin_amdgcn_mfma_f32_16x16x32_bf16(ha, w0l, c0, 0, 0, 0);
    c0 = __builtin_amdgcn_mfma_f32_16x16x32_bf16(hb, w0h, c0, 0, 0, 0);
    c1 = __builtin_amdgcn_mfma_f32_16x16x32_bf16(ha, w1l, c1, 0, 0, 0);
    c1 = __builtin_amdgcn_mfma_f32_16x16x32_bf16(hb, w1h, c1, 0, 0, 0);
    c2 = __builtin_amdgcn_mfma_f32_16x16x32_bf16(ha, w2l, c2, 0, 0, 0);
    c2 = __builtin_amdgcn_mfma_f32_16x16x32_bf16(hb, w2h, c2, 0, 0, 0);
    c3 = __builtin_amdgcn_mfma_f32_16x16x32_bf16(ha, w3l, c3, 0, 0, 0);
    c3 = __builtin_amdgcn_mfma_f32_16x16x32_bf16(hb, w3h, c3, 0, 0, 0);

    // epilogue: xs2[orow, c] = dis[orow] * y   (C layout: col=m, row=q*4+reg)
    #pragma unroll
    for (int reg = 0; reg < 4; ++reg) {
        const int orow = rowbase + q * 4 + reg;
        if (orow < n) {
            const float d2 = dis[orow];
            unsigned short* yp = Y + (size_t)orow * 64 + m;
            yp[0]  = f2bf(d2 * c0[reg]);
            yp[16] = f2bf(d2 * c1[reg]);
            yp[32] = f2bf(d2 * c2[reg]);
            yp[48] = f2bf(d2 * c3[reg]);
        }
    }
}

// agg2 in the same wave layout (16 nodes/wave, 4 lanes/node, 2x16B gathers
// per edge-row: half the load instructions of the 16-lane/node form).
// No MFMA: o = di*acc + b2, bf16 out via two 16B stores.
__global__ __launch_bounds__(256) void agg_wave(const unsigned short* __restrict__ xs,
                                                const int* __restrict__ csr,
                                                const int* __restrict__ offs,
                                                const float* __restrict__ dis,
                                                const float* __restrict__ bias,
                                                unsigned short* __restrict__ Y, int n) {
    const int tid = threadIdx.x;
    const int wv = tid >> 6;
    const int lane = tid & 63;
    const int m = lane & 15;
    const int q = lane >> 4;
    const int rowbase = blockIdx.x * 64 + wv * 16;

    int i = rowbase + m;
    if (i >= n) i = n - 1;           // clamp: dup lanes write identical values
    const int off_lo = q * 8;

    float alo[8], ahi[8];
    {
        const unsigned short* xrow = xs + (size_t)i * 64;
        const short8 s0 = *(const short8*)(xrow + off_lo);
        const short8 s1 = *(const short8*)(xrow + 32 + off_lo);
        #pragma unroll
        for (int j = 0; j < 8; ++j) { alo[j] = bf2f((unsigned short)s0[j]); ahi[j] = bf2f((unsigned short)s1[j]); }
    }

    const int s = offs[i];
    const int e = offs[i + 1];
    int j = s;
    int r0 = 0, r1 = 0, r2 = 0, r3 = 0;
    if (j + 3 < e) { r0 = csr[j]; r1 = csr[j + 1]; r2 = csr[j + 2]; r3 = csr[j + 3]; }
    while (j + 3 < e) {
        const int jn = j + 4;
        const int c0 = min(jn,     e - 1), c1 = min(jn + 1, e - 1);
        const int c2 = min(jn + 2, e - 1), c3 = min(jn + 3, e - 1);
        const int n0 = csr[c0], n1 = csr[c1], n2 = csr[c2], n3 = csr[c3];
        const short8 v0l = *(const short8*)(xs + (size_t)r0 * 64 + off_lo);
        const short8 v0h = *(const short8*)(xs + (size_t)r0 * 64 + 32 + off_lo);
        const short8 v1l = *(const short8*)(xs + (size_t)r1 * 64 + off_lo);
        const short8 v1h = *(const short8*)(xs + (size_t)r1 * 64 + 32 + off_lo);
        const short8 v2l = *(const short8*)(xs + (size_t)r2 * 64 + off_lo);
        const short8 v2h = *(const short8*)(xs + (size_t)r2 * 64 + 32 + off_lo);
        const short8 v3l = *(const short8*)(xs + (size_t)r3 * 64 + off_lo);
        const short8 v3h = *(const short8*)(xs + (size_t)r3 * 64 + 32 + off_lo);
        acc8(alo, v0l); acc8(ahi, v0h);
        acc8(alo, v1l); acc8(ahi, v1h);
        acc8(alo, v2l); acc8(ahi, v2h);
        acc8(alo, v3l); acc8(ahi, v3h);
        r0 = n0; r1 = n1; r2 = n2; r3 = n3;
        j = jn;
    }
    for (; j < e; ++j) {
        const int r = csr[j];
        const short8 vl = *(const short8*)(xs + (size_t)r * 64 + off_lo);
        const short8 vh = *(const short8*)(xs + (size_t)r * 64 + 32 + off_lo);
        acc8(alo, vl); acc8(ahi, vh);
    }

    const float di = dis[i];
    float bl[8], bh[8];
    *(float4*)&bl[0] = *(const float4*)(bias + off_lo);
    *(float4*)&bl[4] = *(const float4*)(bias + off_lo + 4);
    *(float4*)&bh[0] = *(const float4*)(bias + 32 + off_lo);
    *(float4*)&bh[4] = *(const float4*)(bias + 32 + off_lo + 4);
    short8 ol, oh;
    #pragma unroll
    for (int jj = 0; jj < 8; ++jj) {
        ol[jj] = (short)f2bf(fmaf(alo[jj], di, bl[jj]));
        oh[jj] = (short)f2bf(fmaf(ahi[jj], di, bh[jj]));
    }
    *(short8*)(Y + (size_t)i * 64 + off_lo) = ol;
    *(short8*)(Y + (size_t)i * 64 + 32 + off_lo) = oh;
}

// 8 lanes per label edge: bf16 short8 gathers of z[src], z[dst]; 3-step xor
// reduce (within-group shfl: group control flow is uniform, L % 8 == 0).
__global__ __launch_bounds__(256) void decode_kernel(const unsigned short* __restrict__ z,
                                                     const int* __restrict__ src,
                                                     const int* __restrict__ dst,
                                                     float* __restrict__ out, int L) {
    const int t = blockIdx.x * 256 + threadIdx.x;
    const int e = t >> 3;
    const int fl = t & 7;
    if (e >= L) return;
    const int s = src[e];
    const int d = dst[e];
    const short8 a = *(const short8*)&z[(long)s * 64 + fl * 8];
    const short8 b = *(const short8*)&z[(long)d * 64 + fl * 8];
    float p = 0.f;
    #pragma unroll
    for (int j = 0; j < 8; ++j)
        p = fmaf(bf2f((unsigned short)a[j]), bf2f((unsigned short)b[j]), p);
    p += __shfl_xor(p, 4); p += __shfl_xor(p, 2); p += __shfl_xor(p, 1);
    if (fl == 0) out[e] = p;
}

extern "C" void kernel_launch(void* const* d_in, const int* in_sizes, int n_in,
                              void* d_out, int out_size, void* d_ws, size_t ws_size,
                              hipStream_t stream) {
    const float* x   = (const float*)d_in[0];
    const int*   ei  = (const int*)d_in[1];
    const int*   eli = (const int*)d_in[2];
    const float* W1  = (const float*)d_in[3];
    const float* b1  = (const float*)d_in[4];
    const float* W2  = (const float*)d_in[5];
    const float* b2  = (const float*)d_in[6];
    float* out = (float*)d_out;

    const int N = in_sizes[0] / 256;   // 50000 nodes (IN_CH = 256)
    const int E = in_sizes[1] / 2;     // 800000 edges
    const int L = in_sizes[2] / 2;     // 200000 label edges
    const int* row = ei;
    const int* col = ei + E;
    const int* src = eli;
    const int* dst = eli + L;

    char* w = (char*)d_ws;
    unsigned short* xs1 = (unsigned short*)w;  w += (size_t)N * 64 * 2;  // bf16 layer-1 pre-agg
    unsigned short* xs2 = (unsigned short*)w;  w += (size_t)N * 64 * 2;  // bf16 layer-2 pre-agg
    unsigned short* z = (unsigned short*)w;  w += (size_t)N * 64 * 2;    // bf16 layer-2 output
    int*   csr = (int*)w;    w += (size_t)E * 4;          // sources sorted by target
    int*   offs = (int*)w;   w += (size_t)(N + 1) * 4;    // CSR offsets (N+1)
    float* dis = (float*)w;  w += (size_t)N * 4;          // rsqrt(deg+1)
    int*   part = (int*)w;   w += (size_t)E * 4;          // packed (row<<8|col&255)
    int* histBM = (int*)w;   w += (size_t)NBPAD * NC * 4; // per-(bucket,chunk) counts
    int* offsBM = (int*)w;   w += (size_t)NBPAD * NC * 4; // per-(bucket,chunk) offsets
    int* bsums  = (int*)w;   w += NBPAD * 4;              // bucket totals
    unsigned short* Wp1 = (unsigned short*)w;  w += (size_t)256 * 64 * 2;  // packed bf16 W1
    unsigned short* Wp2 = (unsigned short*)w;  w += (size_t)64 * 64 * 2;   // packed bf16 W2

    const int CE = (E + NC - 1) / NC;
    const int nbk = (N + (1 << BSHIFT) - 1) >> BSHIFT;    // 196 buckets

    pack_kernel<<<81, 256, 0, stream>>>(W1, W2, Wp1, Wp2, bsums);
    hist_kernel<<<NC, 256, 0, stream>>>(col, histBM, bsums, E, CE);
    rowscan_kernel<<<NBPAD, 256, 0, stream>>>(histBM, bsums, offsBM);
    reorder_kernel<<<NC, 256, 0, stream>>>(row, col, offsBM, part, E, CE);
    bucket_csr_kernel<<<nbk, 1024, 0, stream>>>(part, offsBM, csr, offs, dis, N, E, nbk);

    gemm_mfma<256><<<(N + 63) / 64, 256, 0, stream>>>(x, Wp1, dis, xs1, N);
    agg_gemm_fused<<<(N + 63) / 64, 256, 0, stream>>>(xs1, csr, offs, dis, b1, Wp2, xs2, N);
    agg_wave<<<(N + 63) / 64, 256, 0, stream>>>(xs2, csr, offs, dis, b2, z, N);
    decode_kernel<<<(L * 8 + 255) / 256, 256, 0, stream>>>(z, src, dst, out, L);
}